// Round 1
// baseline (542.248 us; speedup 1.0000x reference)
//
#include <hip/hip_runtime.h>
#include <math.h>

#define N_TOKENS 16384
#define D_MODEL 2048
#define NUM_EXPERTS 64
#define TOPK 8
#define TOK_PER_BLOCK 8
#define BLOCK_THREADS (TOK_PER_BLOCK * 64)

__global__ __launch_bounds__(BLOCK_THREADS)
void noisy_topk_router_kernel(
    const float* __restrict__ x,        // [N, D]
    const float* __restrict__ eps,      // [N, E]
    const float* __restrict__ Wg,       // [D, E]
    const float* __restrict__ bg,       // [E]
    const float* __restrict__ Wn,       // [D, E]
    const float* __restrict__ bn,       // [E]
    float* __restrict__ out_probs,      // [N, E]
    float* __restrict__ out_idx)        // [N, K] written as float
{
    __shared__ float xs[TOK_PER_BLOCK * D_MODEL];   // 64 KB

    const int tid  = threadIdx.x;
    const int wave = tid >> 6;          // token within block
    const int lane = tid & 63;          // expert index
    const int tok0 = blockIdx.x * TOK_PER_BLOCK;

    // Cooperative load of 8 contiguous x rows into LDS (64 KB, float4).
    {
        const float4* src = reinterpret_cast<const float4*>(x + (size_t)tok0 * D_MODEL);
        float4* dst = reinterpret_cast<float4*>(xs);
        const int nvec = TOK_PER_BLOCK * D_MODEL / 4;   // 4096
        #pragma unroll 4
        for (int i = tid; i < nvec; i += BLOCK_THREADS) dst[i] = src[i];
    }
    __syncthreads();

    const int tok = tok0 + wave;
    const int e   = lane;

    // fp64-accumulated dots: logits = x@Wg, pre-noise = x@Wn
    double ag = 0.0, an = 0.0;
    const float* xrow = xs + wave * D_MODEL;
    #pragma unroll 8
    for (int k = 0; k < D_MODEL; ++k) {
        const double xv = (double)xrow[k];                      // LDS broadcast
        ag = fma(xv, (double)Wg[k * NUM_EXPERTS + e], ag);      // coalesced, L1-hot
        an = fma(xv, (double)Wn[k * NUM_EXPERTS + e], an);
    }

    const double logit = ag + (double)bg[e];
    const double nvv   = an + (double)bn[e];
    // stable softplus in double
    const double sp = (nvv > 0.0) ? (nvv + log1p(exp(-nvv))) : log1p(exp(nvv));
    const double noisy = logit + (double)eps[(size_t)tok * NUM_EXPERTS + e] * sp;

    // Iterative top-8 extraction across the wave (64 lanes = 64 experts).
    // Tie-break: higher value wins; on exact tie, lower index wins (jax.lax.top_k).
    double cur = noisy;         // set to -inf once taken
    double m = 0.0, sum = 0.0;
    int    sel = 0;
    float  my_out_idx = 0.0f;   // valid on lanes 0..7: index of rank-`lane` expert

    #pragma unroll
    for (int r = 0; r < TOPK; ++r) {
        double bv = cur;
        int    bi = lane;
        #pragma unroll
        for (int off = 32; off >= 1; off >>= 1) {
            double ov = __shfl_xor(bv, off);
            int    oi = __shfl_xor(bi, off);
            if (ov > bv || (ov == bv && oi < bi)) { bv = ov; bi = oi; }
        }
        // all lanes now agree on (bv, bi) = rank-r value and expert index
        if (r == 0) m = bv;
        sum += exp(bv - m);
        if (lane == bi) { sel = 1; cur = -INFINITY; }
        if (lane == r)  my_out_idx = (float)bi;
    }

    const double prob = sel ? exp(noisy - m) / sum : 0.0;
    out_probs[(size_t)tok * NUM_EXPERTS + e] = (float)prob;
    if (lane < TOPK) out_idx[(size_t)tok * TOPK + lane] = my_out_idx;
}

extern "C" void kernel_launch(void* const* d_in, const int* in_sizes, int n_in,
                              void* d_out, int out_size, void* d_ws, size_t ws_size,
                              hipStream_t stream) {
    const float* x   = (const float*)d_in[0];
    const float* eps = (const float*)d_in[1];
    const float* Wg  = (const float*)d_in[2];
    const float* bg  = (const float*)d_in[3];
    const float* Wn  = (const float*)d_in[4];
    const float* bn  = (const float*)d_in[5];

    float* out_probs = (float*)d_out;                               // [N, E]
    float* out_idx   = (float*)d_out + (size_t)N_TOKENS * NUM_EXPERTS; // [N, K]

    dim3 grid(N_TOKENS / TOK_PER_BLOCK);
    dim3 block(BLOCK_THREADS);
    noisy_topk_router_kernel<<<grid, block, 0, stream>>>(
        x, eps, Wg, bg, Wn, bn, out_probs, out_idx);
}

// Round 2
// 307.247 us; speedup vs baseline: 1.7649x; 1.7649x over previous
//
#include <hip/hip_runtime.h>
#include <math.h>

#define N_TOKENS 16384
#define D_MODEL 2048
#define NUM_EXPERTS 64
#define TOPK 8
#define WAVES 8
#define BLOCK_THREADS (WAVES * 64)
#define T_PER_WAVE 8
#define TOK_PER_BLOCK (WAVES * T_PER_WAVE)   // 64
#define KC 64
#define NCHUNK (D_MODEL / KC)                // 32

// async global->LDS, 16B per lane, dest = uniform base + lane*16
#define GLD_LDS(g, l) __builtin_amdgcn_global_load_lds( \
    (const __attribute__((address_space(1))) void*)(g), \
    (__attribute__((address_space(3))) void*)(l), 16, 0, 0)

__device__ __forceinline__ float f4c(const float4& v, int j) {
    return j == 0 ? v.x : j == 1 ? v.y : j == 2 ? v.z : v.w;
}

__global__ __launch_bounds__(BLOCK_THREADS, 2)
void noisy_topk_router_kernel(const float* __restrict__ x,
                              const float* __restrict__ eps,
                              const float* __restrict__ Wg,
                              const float* __restrict__ bg,
                              const float* __restrict__ Wn,
                              const float* __restrict__ bn,
                              float* __restrict__ out_probs,
                              float* __restrict__ out_idx)
{
    // [buf][k][0..63 = Wg experts, 64..127 = Wn experts]
    __shared__ float Wbuf[2][KC][128];   // 64 KB

    const int tid  = threadIdx.x;
    const int w    = tid >> 6;
    const int lane = tid & 63;
    const int tok0 = blockIdx.x * TOK_PER_BLOCK + w * T_PER_WAVE;

    // staging lane->source mapping: one instr covers 2 LDS rows (1 KB).
    // lanes 0..31 -> row r, lanes 32..63 -> row r+1.
    // within a row: slots 0..15 = Wg[gk][0..63], slots 16..31 = Wn[gk][0..63]
    const int rhalf = lane >> 5;
    const int q     = lane & 31;
    const int col4  = (q & 15) * 4;
    const bool isWn = q >= 16;

    float ag[T_PER_WAVE], an[T_PER_WAVE];
    double dg[T_PER_WAVE], dn[T_PER_WAVE];
    #pragma unroll
    for (int t = 0; t < T_PER_WAVE; ++t) { ag[t] = 0.f; an[t] = 0.f; dg[t] = 0.0; dn[t] = 0.0; }

    const float4* xp[T_PER_WAVE];
    #pragma unroll
    for (int t = 0; t < T_PER_WAVE; ++t)
        xp[t] = reinterpret_cast<const float4*>(x + (size_t)(tok0 + t) * D_MODEL);

    // ---- stage chunk 0 ----
    {
        #pragma unroll
        for (int i = 0; i < 4; ++i) {
            const int rloc = w * 8 + i * 2;
            const int gk   = 0 * KC + rloc + rhalf;
            const float* src = (isWn ? Wn : Wg) + (size_t)gk * NUM_EXPERTS + col4;
            GLD_LDS(src, &Wbuf[0][rloc][0]);
        }
    }
    __syncthreads();   // vmcnt(0) drained before barrier -> buf0 ready

    for (int c = 0; c < NCHUNK; ++c) {
        const int b = c & 1;
        if (c + 1 < NCHUNK) {
            #pragma unroll
            for (int i = 0; i < 4; ++i) {
                const int rloc = w * 8 + i * 2;
                const int gk   = (c + 1) * KC + rloc + rhalf;
                const float* src = (isWn ? Wn : Wg) + (size_t)gk * NUM_EXPERTS + col4;
                GLD_LDS(src, &Wbuf[b ^ 1][rloc][0]);
            }
        }

        #pragma unroll
        for (int half = 0; half < 2; ++half) {
            #pragma unroll
            for (int g = 0; g < 8; ++g) {
                const int kk = half * 32 + g * 4;
                float4 xv[T_PER_WAVE];
                #pragma unroll
                for (int t = 0; t < T_PER_WAVE; ++t)
                    xv[t] = xp[t][c * (KC / 4) + (kk >> 2)];   // wave-uniform addr, L1 broadcast
                #pragma unroll
                for (int j = 0; j < 4; ++j) {
                    const float wg = Wbuf[b][kk + j][lane];
                    const float wn = Wbuf[b][kk + j][64 + lane];
                    #pragma unroll
                    for (int t = 0; t < T_PER_WAVE; ++t) {
                        ag[t] = fmaf(f4c(xv[t], j), wg, ag[t]);
                        an[t] = fmaf(f4c(xv[t], j), wn, an[t]);
                    }
                }
            }
            // fold fp32 partials into fp64 every 32 k (error ~2e-7 rms)
            #pragma unroll
            for (int t = 0; t < T_PER_WAVE; ++t) {
                dg[t] += (double)ag[t]; ag[t] = 0.f;
                dn[t] += (double)an[t]; an[t] = 0.f;
            }
        }
        __syncthreads();   // drains stage(c+1); gates buffer reuse
    }

    // ---- epilogue: softplus + noise + top-8 + sparse softmax (per token) ----
    const float bgv = bg[lane];
    const float bnv = bn[lane];

    #pragma unroll 1
    for (int t = 0; t < T_PER_WAVE; ++t) {
        const int tok = tok0 + t;
        const double logit = dg[t] + (double)bgv;
        const double nvv   = dn[t] + (double)bnv;
        const double sp    = (nvv > 0.0) ? (nvv + log1p(exp(-nvv))) : log1p(exp(nvv));
        const double noisy = logit + (double)eps[(size_t)tok * NUM_EXPERTS + lane] * sp;

        // iterative top-8; tie-break: higher value, then lower index (lax.top_k)
        double cur = noisy;
        double m = 0.0, sum = 0.0;
        int    sel = 0;
        float  my_idx = 0.0f;
        #pragma unroll
        for (int r = 0; r < TOPK; ++r) {
            double bv = cur;
            int    bi = lane;
            #pragma unroll
            for (int off = 32; off >= 1; off >>= 1) {
                double ov = __shfl_xor(bv, off);
                int    oi = __shfl_xor(bi, off);
                if (ov > bv || (ov == bv && oi < bi)) { bv = ov; bi = oi; }
            }
            if (r == 0) m = bv;
            sum += exp(bv - m);
            if (lane == bi) { sel = 1; cur = -INFINITY; }
            if (lane == r)  my_idx = (float)bi;
        }

        out_probs[(size_t)tok * NUM_EXPERTS + lane] = (float)(sel ? exp(noisy - m) / sum : 0.0);
        if (lane < TOPK) out_idx[(size_t)tok * TOPK + lane] = my_idx;
    }
}

extern "C" void kernel_launch(void* const* d_in, const int* in_sizes, int n_in,
                              void* d_out, int out_size, void* d_ws, size_t ws_size,
                              hipStream_t stream) {
    const float* x   = (const float*)d_in[0];
    const float* eps = (const float*)d_in[1];
    const float* Wg  = (const float*)d_in[2];
    const float* bg  = (const float*)d_in[3];
    const float* Wn  = (const float*)d_in[4];
    const float* bn  = (const float*)d_in[5];

    float* out_probs = (float*)d_out;                                  // [N, E]
    float* out_idx   = (float*)d_out + (size_t)N_TOKENS * NUM_EXPERTS; // [N, K]

    dim3 grid(N_TOKENS / TOK_PER_BLOCK);   // 256
    dim3 block(BLOCK_THREADS);             // 512
    noisy_topk_router_kernel<<<grid, block, 0, stream>>>(
        x, eps, Wg, bg, Wn, bn, out_probs, out_idx);
}

// Round 3
// 285.243 us; speedup vs baseline: 1.9010x; 1.0771x over previous
//
#include <hip/hip_runtime.h>
#include <math.h>

#define N_TOKENS 16384
#define D_MODEL 2048
#define NUM_EXPERTS 64
#define TOPK 8
#define BLOCK_THREADS 512           // 8 waves: 4 token-groups x 2 roles
#define T_PER_GROUP 8
#define TOK_PER_BLOCK 32
#define NSTEP4 (D_MODEL / 4)        // 512 float4 steps per row

__device__ __forceinline__ float f4c(const float4& v, int j) {
    return j == 0 ? v.x : j == 1 ? v.y : j == 2 ? v.z : v.w;
}

// Pre-pass: WT4[kk][col] (col = role*64 + e) = {W_role[4kk+j][e], j=0..3}
// so the main loop's W read is one coalesced dwordx4 per 4 k's per lane.
__global__ __launch_bounds__(256)
void wt_build_kernel(const float* __restrict__ Wg, const float* __restrict__ Wn,
                     float4* __restrict__ WT4) {
    const int id  = blockIdx.x * 256 + threadIdx.x;    // 0..65535
    const int kk  = id >> 7;
    const int col = id & 127;
    const int ro  = col >> 6;
    const int e   = col & 63;
    const float* src = (ro ? Wn : Wg) + (size_t)(kk * 4) * NUM_EXPERTS + e;
    WT4[id] = make_float4(src[0], src[NUM_EXPERTS], src[2 * NUM_EXPERTS], src[3 * NUM_EXPERTS]);
}

__global__ __launch_bounds__(BLOCK_THREADS, 4)
void noisy_topk_router_kernel(const float* __restrict__ x,
                              const float* __restrict__ eps,
                              const float4* __restrict__ WT4,
                              const float* __restrict__ bg,
                              const float* __restrict__ bn,
                              float* __restrict__ out_probs,
                              float* __restrict__ out_idx)
{
    __shared__ double exbuf[2][TOK_PER_BLOCK][NUM_EXPERTS];   // 32 KB

    const int tid  = threadIdx.x;
    const int lane = tid & 63;
    const int w    = __builtin_amdgcn_readfirstlane(tid >> 6);  // wave id (uniform)
    const int gi   = w >> 1;          // token group 0..3
    const int ro   = w & 1;           // 0 = gate, 1 = noise
    const int btok0 = blockIdx.x * TOK_PER_BLOCK;
    const int tok0  = btok0 + gi * T_PER_GROUP;

    const float4* xb[T_PER_GROUP];
    #pragma unroll
    for (int t = 0; t < T_PER_GROUP; ++t)
        xb[t] = reinterpret_cast<const float4*>(x) + (size_t)(tok0 + t) * NSTEP4;

    // this wave's W stream: one float4 (4 k's) per step, coalesced across lanes
    const float4* wtp = WT4 + ro * 64 + lane;   // advance by 128 float4 per step

    float  ag[T_PER_GROUP];
    double dd[T_PER_GROUP];
    #pragma unroll
    for (int t = 0; t < T_PER_GROUP; ++t) { ag[t] = 0.f; dd[t] = 0.0; }

    // 64 half-spans of 32 k (8 float4-steps); fp64 fold + convoy barrier per span
    for (int h = 0; h < 64; ++h) {
        const int i0 = h * 8;
        #pragma unroll
        for (int s = 0; s < 8; ++s) {
            const int i = i0 + s;
            const float4 wt = wtp[(size_t)i * 128];
            float4 xv[T_PER_GROUP];
            #pragma unroll
            for (int t = 0; t < T_PER_GROUP; ++t) xv[t] = xb[t][i];
            #pragma unroll
            for (int j = 0; j < 4; ++j) {
                const float wj = f4c(wt, j);
                #pragma unroll
                for (int t = 0; t < T_PER_GROUP; ++t)
                    ag[t] = fmaf(f4c(xv[t], j), wj, ag[t]);
            }
        }
        #pragma unroll
        for (int t = 0; t < T_PER_GROUP; ++t) { dd[t] += (double)ag[t]; ag[t] = 0.f; }
        __builtin_amdgcn_s_barrier();   // convoy only — no LDS/global deps here
    }

    // exchange: role 0 deposits gate dots, role 1 noise dots
    #pragma unroll
    for (int t = 0; t < T_PER_GROUP; ++t)
        exbuf[ro][gi * T_PER_GROUP + t][lane] = dd[t];
    __syncthreads();

    // epilogue: each wave finishes 4 tokens (softplus + noise + top-8 + softmax)
    const float bgv = bg[lane];
    const float bnv = bn[lane];

    #pragma unroll 1
    for (int q = 0; q < 4; ++q) {
        const int tt  = w * 4 + q;
        const int tok = btok0 + tt;
        const double logit = exbuf[0][tt][lane] + (double)bgv;
        const double nvv   = exbuf[1][tt][lane] + (double)bnv;
        const double sp    = (nvv > 0.0) ? (nvv + log1p(exp(-nvv))) : log1p(exp(nvv));
        const double noisy = logit + (double)eps[(size_t)tok * NUM_EXPERTS + lane] * sp;

        // iterative top-8; tie-break: higher value, then lower index (lax.top_k)
        double cur = noisy;
        double m = 0.0, sum = 0.0;
        int    sel = 0;
        float  my_idx = 0.0f;
        #pragma unroll
        for (int rk = 0; rk < TOPK; ++rk) {
            double bv = cur;
            int    bi = lane;
            #pragma unroll
            for (int off = 32; off >= 1; off >>= 1) {
                double ov = __shfl_xor(bv, off);
                int    oi = __shfl_xor(bi, off);
                if (ov > bv || (ov == bv && oi < bi)) { bv = ov; bi = oi; }
            }
            if (rk == 0) m = bv;
            sum += exp(bv - m);
            if (lane == bi) { sel = 1; cur = -INFINITY; }
            if (lane == rk) my_idx = (float)bi;
        }

        out_probs[(size_t)tok * NUM_EXPERTS + lane] = (float)(sel ? exp(noisy - m) / sum : 0.0);
        if (lane < TOPK) out_idx[(size_t)tok * TOPK + lane] = my_idx;
    }
}

extern "C" void kernel_launch(void* const* d_in, const int* in_sizes, int n_in,
                              void* d_out, int out_size, void* d_ws, size_t ws_size,
                              hipStream_t stream) {
    const float* x   = (const float*)d_in[0];
    const float* eps = (const float*)d_in[1];
    const float* Wg  = (const float*)d_in[2];
    const float* bg  = (const float*)d_in[3];
    const float* Wn  = (const float*)d_in[4];
    const float* bn  = (const float*)d_in[5];

    float* out_probs = (float*)d_out;                                  // [N, E]
    float* out_idx   = (float*)d_out + (size_t)N_TOKENS * NUM_EXPERTS; // [N, K]

    float4* WT4 = (float4*)d_ws;    // 512 * 128 * 16 B = 1 MB

    wt_build_kernel<<<dim3(256), dim3(256), 0, stream>>>(Wg, Wn, WT4);

    dim3 grid(N_TOKENS / TOK_PER_BLOCK);   // 512
    dim3 block(BLOCK_THREADS);             // 512
    noisy_topk_router_kernel<<<grid, block, 0, stream>>>(
        x, eps, WT4, bg, bn, out_probs, out_idx);
}

// Round 4
// 285.237 us; speedup vs baseline: 1.9010x; 1.0000x over previous
//
#include <hip/hip_runtime.h>
#include <math.h>

#define N_TOKENS 16384
#define D_MODEL 2048
#define NUM_EXPERTS 64
#define TOPK 8
#define BLOCK_THREADS 512           // 8 waves: 4 token-groups x 2 roles
#define T_PER_GROUP 8
#define TOK_PER_BLOCK 32
#define NSTEP4 (D_MODEL / 4)        // 512 float4 steps per row

__device__ __forceinline__ float f4c(const float4& v, int j) {
    return j == 0 ? v.x : j == 1 ? v.y : j == 2 ? v.z : v.w;
}

// Pre-pass: WT4[kk][col] (col = role*64 + e) = {W_role[4kk+j][e], j=0..3}
// so the main loop's W read is one coalesced dwordx4 per 4 k's per lane.
__global__ __launch_bounds__(256)
void wt_build_kernel(const float* __restrict__ Wg, const float* __restrict__ Wn,
                     float4* __restrict__ WT4) {
    const int id  = blockIdx.x * 256 + threadIdx.x;    // 0..65535
    const int kk  = id >> 7;
    const int col = id & 127;
    const int ro  = col >> 6;
    const int e   = col & 63;
    const float* src = (ro ? Wn : Wg) + (size_t)(kk * 4) * NUM_EXPERTS + e;
    WT4[id] = make_float4(src[0], src[NUM_EXPERTS], src[2 * NUM_EXPERTS], src[3 * NUM_EXPERTS]);
}

__global__ __launch_bounds__(BLOCK_THREADS, 4)
void noisy_topk_router_kernel(const float* __restrict__ x,
                              const float* __restrict__ eps,
                              const float4* __restrict__ WT4,
                              const float* __restrict__ bg,
                              const float* __restrict__ bn,
                              float* __restrict__ out_probs,
                              float* __restrict__ out_idx)
{
    __shared__ double exbuf[2][TOK_PER_BLOCK][NUM_EXPERTS];   // 32 KB

    const int tid  = threadIdx.x;
    const int lane = tid & 63;
    const int w    = __builtin_amdgcn_readfirstlane(tid >> 6);  // wave id (uniform)
    const int gi   = w >> 1;          // token group 0..3
    const int ro   = w & 1;           // 0 = gate, 1 = noise
    const int btok0 = blockIdx.x * TOK_PER_BLOCK;
    const int tok0  = btok0 + gi * T_PER_GROUP;

    const float4* xb[T_PER_GROUP];
    #pragma unroll
    for (int t = 0; t < T_PER_GROUP; ++t)
        xb[t] = reinterpret_cast<const float4*>(x) + (size_t)(tok0 + t) * NSTEP4;

    // this wave's W stream: one float4 (4 k's) per step, coalesced across lanes
    const float4* wtp = WT4 + ro * 64 + lane;   // advance by 128 float4 per step

    float  ag[T_PER_GROUP];
    double dd[T_PER_GROUP];
    #pragma unroll
    for (int t = 0; t < T_PER_GROUP; ++t) { ag[t] = 0.f; dd[t] = 0.0; }

    // 64 half-spans of 32 k (8 float4-steps); fp64 fold + convoy barrier per span
    for (int h = 0; h < 64; ++h) {
        const int i0 = h * 8;
        #pragma unroll
        for (int s = 0; s < 8; ++s) {
            const int i = i0 + s;
            const float4 wt = wtp[(size_t)i * 128];
            float4 xv[T_PER_GROUP];
            #pragma unroll
            for (int t = 0; t < T_PER_GROUP; ++t) xv[t] = xb[t][i];
            #pragma unroll
            for (int j = 0; j < 4; ++j) {
                const float wj = f4c(wt, j);
                #pragma unroll
                for (int t = 0; t < T_PER_GROUP; ++t)
                    ag[t] = fmaf(f4c(xv[t], j), wj, ag[t]);
            }
        }
        #pragma unroll
        for (int t = 0; t < T_PER_GROUP; ++t) { dd[t] += (double)ag[t]; ag[t] = 0.f; }
        __builtin_amdgcn_s_barrier();   // convoy only — no LDS/global deps here
    }

    // exchange: role 0 deposits gate dots, role 1 noise dots
    #pragma unroll
    for (int t = 0; t < T_PER_GROUP; ++t)
        exbuf[ro][gi * T_PER_GROUP + t][lane] = dd[t];
    __syncthreads();

    // epilogue: each wave finishes 4 tokens (softplus + noise + top-8 + softmax)
    const float bgv = bg[lane];
    const float bnv = bn[lane];

    #pragma unroll 1
    for (int q = 0; q < 4; ++q) {
        const int tt  = w * 4 + q;
        const int tok = btok0 + tt;
        const double logit = exbuf[0][tt][lane] + (double)bgv;
        const double nvv   = exbuf[1][tt][lane] + (double)bnv;
        const double sp    = (nvv > 0.0) ? (nvv + log1p(exp(-nvv))) : log1p(exp(nvv));
        const double noisy = logit + (double)eps[(size_t)tok * NUM_EXPERTS + lane] * sp;

        // iterative top-8; tie-break: higher value, then lower index (lax.top_k)
        double cur = noisy;
        double m = 0.0, sum = 0.0;
        int    sel = 0;
        float  my_idx = 0.0f;
        #pragma unroll
        for (int rk = 0; rk < TOPK; ++rk) {
            double bv = cur;
            int    bi = lane;
            #pragma unroll
            for (int off = 32; off >= 1; off >>= 1) {
                double ov = __shfl_xor(bv, off);
                int    oi = __shfl_xor(bi, off);
                if (ov > bv || (ov == bv && oi < bi)) { bv = ov; bi = oi; }
            }
            if (rk == 0) m = bv;
            sum += exp(bv - m);
            if (lane == bi) { sel = 1; cur = -INFINITY; }
            if (lane == rk) my_idx = (float)bi;
        }

        out_probs[(size_t)tok * NUM_EXPERTS + lane] = (float)(sel ? exp(noisy - m) / sum : 0.0);
        if (lane < TOPK) out_idx[(size_t)tok * TOPK + lane] = my_idx;
    }
}

extern "C" void kernel_launch(void* const* d_in, const int* in_sizes, int n_in,
                              void* d_out, int out_size, void* d_ws, size_t ws_size,
                              hipStream_t stream) {
    const float* x   = (const float*)d_in[0];
    const float* eps = (const float*)d_in[1];
    const float* Wg  = (const float*)d_in[2];
    const float* bg  = (const float*)d_in[3];
    const float* Wn  = (const float*)d_in[4];
    const float* bn  = (const float*)d_in[5];

    float* out_probs = (float*)d_out;                                  // [N, E]
    float* out_idx   = (float*)d_out + (size_t)N_TOKENS * NUM_EXPERTS; // [N, K]

    float4* WT4 = (float4*)d_ws;    // 512 * 128 * 16 B = 1 MB

    wt_build_kernel<<<dim3(256), dim3(256), 0, stream>>>(Wg, Wn, WT4);

    dim3 grid(N_TOKENS / TOK_PER_BLOCK);   // 512
    dim3 block(BLOCK_THREADS);             // 512
    noisy_topk_router_kernel<<<grid, block, 0, stream>>>(
        x, eps, WT4, bg, bn, out_probs, out_idx);
}